// Round 1
// baseline (152.163 us; speedup 1.0000x reference)
//
#include <hip/hip_runtime.h>
#include <hip/hip_bf16.h>
#include <math.h>

#define B_       512
#define SEQ_     25
#define C_       512
#define W_       5
#define BS_      2560          // B_*W_ rows per input
#define N_       5120          // 2*BS_
#define NT_      40            // N_/128 tile rows
#define NTILES_  (NT_ * (NT_ + 1) / 2)   // 820 upper-triangle tiles
#define CB4_     256           // bytes per zn row (512 fp4 nibbles)
#define TEMP_INV 10.0f
#define EPS_     1e-8f

typedef __attribute__((ext_vector_type(4))) int   int4v;
typedef __attribute__((ext_vector_type(8))) int   int8v;
typedef __attribute__((ext_vector_type(4))) float floatx4;

#define GAS(p) ((__attribute__((address_space(1))) void*)(void*)(p))
#define LAS(p) ((__attribute__((address_space(3))) void*)(p))

// e2m1 quantize of x (pre-scaled by 32): codes 0..7 = {0,.5,1,1.5,2,3,4,6}
static __device__ __forceinline__ uint fp4q(float x) {
    float m = fabsf(x);
    uint c;
    if      (m < 0.25f) c = 0;
    else if (m < 0.75f) c = 1;
    else if (m < 1.25f) c = 2;
    else if (m < 1.75f) c = 3;
    else if (m < 2.5f)  c = 4;
    else if (m < 3.5f)  c = 5;
    else if (m < 5.0f)  c = 6;
    else                c = 7;
    return c | (x < 0.f ? 8u : 0u);
}

// ---- kernel 1: pool (5-wide bins) + L2 normalize + fp4(e2m1) pack -----------
// Also zero-inits S[] and the tile-completion counter (stream order guarantees
// these land before simexp_mfma's atomics — re-poison safe).
__global__ __launch_bounds__(256) void pool_norm_kernel(const float* __restrict__ zi,
                                                        const float* __restrict__ zj,
                                                        uint* __restrict__ zn4,
                                                        float* __restrict__ S,
                                                        int* __restrict__ tc) {
    int row = blockIdx.x * 4 + (threadIdx.x >> 6);
    int lane = threadIdx.x & 63;
    const float* src = (row < BS_) ? zi : zj;
    int rr = (row < BS_) ? row : row - BS_;
    int b = rr / W_;
    int w = rr - b * W_;
    const float4* base4 = (const float4*)(src + ((size_t)b * SEQ_ + (size_t)w * W_) * C_);
    float4 v0 = {0, 0, 0, 0}, v1 = {0, 0, 0, 0};
#pragma unroll
    for (int t = 0; t < W_; ++t) {
        float4 a = base4[t * 128 + lane * 2];
        float4 c = base4[t * 128 + lane * 2 + 1];
        v0.x += a.x; v0.y += a.y; v0.z += a.z; v0.w += a.w;
        v1.x += c.x; v1.y += c.y; v1.z += c.z; v1.w += c.w;
    }
    float ss = v0.x * v0.x + v0.y * v0.y + v0.z * v0.z + v0.w * v0.w
             + v1.x * v1.x + v1.y * v1.y + v1.z * v1.z + v1.w * v1.w;
#pragma unroll
    for (int m = 32; m >= 1; m >>= 1) ss += __shfl_xor(ss, m, 64);
    // 1/5 pooling scale folds into 1/norm (cosine is scale-invariant)
    float inv32 = 32.0f / fmaxf(sqrtf(ss), EPS_);
    uint p = fp4q(v0.x * inv32);
    p |= fp4q(v0.y * inv32) << 4;
    p |= fp4q(v0.z * inv32) << 8;
    p |= fp4q(v0.w * inv32) << 12;
    p |= fp4q(v1.x * inv32) << 16;
    p |= fp4q(v1.y * inv32) << 20;
    p |= fp4q(v1.z * inv32) << 24;
    p |= fp4q(v1.w * inv32) << 28;
    zn4[(size_t)row * 64 + lane] = p;
    if (lane == 0) S[row] = 0.f;                    // replaces memset launch
    if (row == 0 && lane == 0) tc[0] = 0;           // tile-completion counter
}

// ---- kernel 2: upper-tri 128x128 tiles, MX-fp4, double-buffered staging -----
// R4 structure (4 K-iters of 64B/row) + ping-pong LDS: iter k+1's
// global_load_lds issue right after the barrier, ahead of iter k's MFMAs, so
// L2 latency hides behind compute instead of serializing at each drain.
// Loss reduction fused via last-block-done pattern (saves one graph node).
__global__ __launch_bounds__(256) void simexp_mfma(const unsigned char* __restrict__ zn,
                                                   float* __restrict__ S,
                                                   float* __restrict__ pos,
                                                   float* __restrict__ out,
                                                   int* __restrict__ tc) {
    __shared__ __align__(16) unsigned char As[2][128 * 64];   // 2 x 8 KB
    __shared__ __align__(16) unsigned char Bs[2][128 * 64];   // 2 x 8 KB
    // decode upper-triangle tile index (scalar, uniform)
    int t = blockIdx.x, rt = 0, rem = NT_;
    while (t >= rem) { t -= rem; rem--; rt++; }
    int ct = rt + t;

    int tid = threadIdx.x;
    int wid = tid >> 6, lane = tid & 63;
    int lrow = lane >> 2, lk = lane & 3;        // staging: 16 rows x 4 chunks of 16B
    int lx = lane & 15, quad = lane >> 4;       // mfma fragment indexing
    int wrow = (wid >> 1) * 64, wcol = (wid & 1) * 64;

    const unsigned char* gA[2]; const unsigned char* gB[2];
    int loff[2];
#pragma unroll
    for (int c = 0; c < 2; ++c) {
        int r = wid * 32 + c * 16 + lrow;
        gA[c] = zn + (size_t)(rt * 128 + r) * CB4_ + ((lk ^ (lrow & 3)) * 16);
        gB[c] = zn + (size_t)(ct * 128 + r) * CB4_ + ((lk ^ (lrow & 3)) * 16);
        loff[c] = (wid * 32 + c * 16) * 64;     // HW appends lane*16B
    }

    union frag { int8v v8; int4v v4[2]; };
    floatx4 acc[4][4] = {};

    // prologue: stage iter 0 into buffer 0
#pragma unroll
    for (int c = 0; c < 2; ++c) {
        __builtin_amdgcn_global_load_lds(GAS(gA[c]), LAS(As[0] + loff[c]), 16, 0, 0);
        __builtin_amdgcn_global_load_lds(GAS(gB[c]), LAS(Bs[0] + loff[c]), 16, 0, 0);
    }

    for (int k = 0; k < 4; ++k) {               // 4 iters, 128 K-elems each
        int cur = k & 1, nxt = cur ^ 1;
        __syncthreads();                        // buf[cur] ready (vmcnt drained)
        if (k < 3) {                            // prefetch iter k+1 into buf[nxt]
            int k0 = (k + 1) * 64;
#pragma unroll
            for (int c = 0; c < 2; ++c) {
                __builtin_amdgcn_global_load_lds(GAS(gA[c] + k0), LAS(As[nxt] + loff[c]), 16, 0, 0);
                __builtin_amdgcn_global_load_lds(GAS(gB[c] + k0), LAS(Bs[nxt] + loff[c]), 16, 0, 0);
            }
        }
        frag af[4], bf[4];
#pragma unroll
        for (int tt = 0; tt < 4; ++tt) {
            int m = wrow + tt * 16 + lx;
            af[tt].v4[0] = *(const int4v*)&As[cur][m * 64 + ((quad ^ (m & 3)) * 16)];
            af[tt].v4[1] = (int4v)(0);
            int n = wcol + tt * 16 + lx;
            bf[tt].v4[0] = *(const int4v*)&Bs[cur][n * 64 + ((quad ^ (n & 3)) * 16)];
            bf[tt].v4[1] = (int4v)(0);
        }
#pragma unroll
        for (int i = 0; i < 4; ++i)
#pragma unroll
            for (int j = 0; j < 4; ++j)
                acc[i][j] = __builtin_amdgcn_mfma_scale_f32_16x16x128_f8f6f4(
                    af[i].v8, bf[j].v8, acc[i][j],
                    4, 4,                    // cbsz=fp4(e2m1), blgp=fp4(e2m1)
                    0, 0x7A7A7A7A,           // scale A: E8M0 2^-5
                    0, 0x7A7A7A7A);          // scale B: E8M0 2^-5
    }

    // epilogue: D layout col=lane&15, row=quad*4+reg (shape-determined)
    int colb = ct * 128 + wcol + lx;
    if (rt == ct) {
        // diagonal tile: mask diagonal, row sums only (pos never here)
#pragma unroll
        for (int i = 0; i < 4; ++i) {
#pragma unroll
            for (int r = 0; r < 4; ++r) {
                int m = rt * 128 + wrow + i * 16 + quad * 4 + r;
                float s = 0.f;
#pragma unroll
                for (int j = 0; j < 4; ++j) {
                    int cg = colb + j * 16;
                    float e = __expf(acc[i][j][r] * TEMP_INV);
                    if (cg == m) e = 0.f;
                    s += e;
                }
                s += __shfl_xor(s, 1, 64);
                s += __shfl_xor(s, 2, 64);
                s += __shfl_xor(s, 4, 64);
                s += __shfl_xor(s, 8, 64);
                if (lx == 0) atomicAdd(&S[m], s);
            }
        }
    } else {
        // off-diagonal: row sums + column sums (transposed half), pos capture
        float colpart[4] = {0.f, 0.f, 0.f, 0.f};
#pragma unroll
        for (int i = 0; i < 4; ++i) {
#pragma unroll
            for (int r = 0; r < 4; ++r) {
                int m = rt * 128 + wrow + i * 16 + quad * 4 + r;
                int partner = m + BS_;          // only m<BS_ can hit in upper triangle
                float s = 0.f;
#pragma unroll
                for (int j = 0; j < 4; ++j) {
                    int cg = colb + j * 16;
                    float logit = acc[i][j][r] * TEMP_INV;
                    float e = __expf(logit);
                    if (cg == partner) { pos[m] = logit; pos[cg] = logit; }
                    s += e;
                    colpart[j] += e;
                }
                s += __shfl_xor(s, 1, 64);
                s += __shfl_xor(s, 2, 64);
                s += __shfl_xor(s, 4, 64);
                s += __shfl_xor(s, 8, 64);
                if (lx == 0) atomicAdd(&S[m], s);
            }
        }
#pragma unroll
        for (int j = 0; j < 4; ++j) {
            float cs = colpart[j];
            cs += __shfl_xor(cs, 16, 64);
            cs += __shfl_xor(cs, 32, 64);
            if (quad == 0) atomicAdd(&S[colb + j * 16], cs);
        }
    }

    // ---- fused loss: last block to finish reduces sum(log(S)-pos)/N --------
    __threadfence();                            // release S/pos writes (device scope)
    __shared__ int lastBlk;
    if (tid == 0) lastBlk = (atomicAdd(tc, 1) == NTILES_ - 1);
    __syncthreads();
    if (lastBlk) {
        __threadfence();                        // acquire: invalidate stale L2 lines
        float a = 0.f;
#pragma unroll 4
        for (int i = tid; i < N_; i += 256)
            a += logf(S[i]) - pos[i];
#pragma unroll
        for (int m = 32; m >= 1; m >>= 1) a += __shfl_xor(a, m, 64);
        __shared__ float part[4];
        if ((tid & 63) == 0) part[tid >> 6] = a;
        __syncthreads();
        if (tid == 0)
            out[0] = (part[0] + part[1] + part[2] + part[3]) * (1.0f / N_);
    }
}

extern "C" void kernel_launch(void* const* d_in, const int* in_sizes, int n_in,
                              void* d_out, int out_size, void* d_ws, size_t ws_size,
                              hipStream_t stream) {
    const float* zi = (const float*)d_in[0];
    const float* zj = (const float*)d_in[1];
    float* out = (float*)d_out;

    char* ws = (char*)d_ws;
    unsigned char* zn = (unsigned char*)ws;                    // N_*256 B fp4 = 1.31 MB
    float* S   = (float*)(ws + (size_t)N_ * CB4_);
    float* pos = S + N_;
    int* tc    = (int*)(pos + N_);

    pool_norm_kernel<<<N_ / 4, 256, 0, stream>>>(zi, zj, (uint*)zn, S, tc);
    simexp_mfma<<<NTILES_, 256, 0, stream>>>(zn, S, pos, out, tc);
}

// Round 2
// 113.169 us; speedup vs baseline: 1.3446x; 1.3446x over previous
//
#include <hip/hip_runtime.h>
#include <hip/hip_bf16.h>
#include <math.h>

#define B_       512
#define SEQ_     25
#define C_       512
#define W_       5
#define BS_      2560          // B_*W_ rows per input
#define N_       5120          // 2*BS_
#define NT_      40            // N_/128 tile rows
#define NTILES_  (NT_ * (NT_ + 1) / 2)   // 820 upper-triangle tiles
#define CB4_     256           // bytes per zn row (512 fp4 nibbles)
#define NSLOT_   80            // 2 partial slots per tile row/col (col-half, row-half)
#define TEMP_INV 10.0f
#define EPS_     1e-8f

typedef __attribute__((ext_vector_type(4))) int   int4v;
typedef __attribute__((ext_vector_type(8))) int   int8v;
typedef __attribute__((ext_vector_type(4))) float floatx4;

#define GAS(p) ((__attribute__((address_space(1))) void*)(void*)(p))
#define LAS(p) ((__attribute__((address_space(3))) void*)(p))

// e2m1 quantize of x (pre-scaled by 32): codes 0..7 = {0,.5,1,1.5,2,3,4,6}
static __device__ __forceinline__ uint fp4q(float x) {
    float m = fabsf(x);
    uint c;
    if      (m < 0.25f) c = 0;
    else if (m < 0.75f) c = 1;
    else if (m < 1.25f) c = 2;
    else if (m < 1.75f) c = 3;
    else if (m < 2.5f)  c = 4;
    else if (m < 3.5f)  c = 5;
    else if (m < 5.0f)  c = 6;
    else                c = 7;
    return c | (x < 0.f ? 8u : 0u);
}

// ---- kernel 1: pool (5-wide bins) + L2 normalize + fp4(e2m1) pack -----------
__global__ __launch_bounds__(256) void pool_norm_kernel(const float* __restrict__ zi,
                                                        const float* __restrict__ zj,
                                                        uint* __restrict__ zn4,
                                                        float* __restrict__ out) {
    int row = blockIdx.x * 4 + (threadIdx.x >> 6);
    int lane = threadIdx.x & 63;
    const float* src = (row < BS_) ? zi : zj;
    int rr = (row < BS_) ? row : row - BS_;
    int b = rr / W_;
    int w = rr - b * W_;
    const float4* base4 = (const float4*)(src + ((size_t)b * SEQ_ + (size_t)w * W_) * C_);
    float4 v0 = {0, 0, 0, 0}, v1 = {0, 0, 0, 0};
#pragma unroll
    for (int t = 0; t < W_; ++t) {
        float4 a = base4[t * 128 + lane * 2];
        float4 c = base4[t * 128 + lane * 2 + 1];
        v0.x += a.x; v0.y += a.y; v0.z += a.z; v0.w += a.w;
        v1.x += c.x; v1.y += c.y; v1.z += c.z; v1.w += c.w;
    }
    float ss = v0.x * v0.x + v0.y * v0.y + v0.z * v0.z + v0.w * v0.w
             + v1.x * v1.x + v1.y * v1.y + v1.z * v1.z + v1.w * v1.w;
#pragma unroll
    for (int m = 32; m >= 1; m >>= 1) ss += __shfl_xor(ss, m, 64);
    // 1/5 pooling scale folds into 1/norm (cosine is scale-invariant)
    float inv32 = 32.0f / fmaxf(sqrtf(ss), EPS_);
    uint p = fp4q(v0.x * inv32);
    p |= fp4q(v0.y * inv32) << 4;
    p |= fp4q(v0.z * inv32) << 8;
    p |= fp4q(v0.w * inv32) << 12;
    p |= fp4q(v1.x * inv32) << 16;
    p |= fp4q(v1.y * inv32) << 20;
    p |= fp4q(v1.z * inv32) << 24;
    p |= fp4q(v1.w * inv32) << 28;
    zn4[(size_t)row * 64 + lane] = p;
    if (row == 0 && lane == 0) out[0] = 0.f;        // loss accumulator init
}

// ---- kernel 2: upper-tri 128x128 tiles, MX-fp4, double-buffered staging -----
// R4 structure (4 K-iters of 64B/row) + ping-pong LDS. Epilogue writes
// ATOMIC-FREE partials: PART[row][slot], slot = tile*2 + half, exactly one
// writer per slot (row side: col-half waves; col side: row-half waves).
// Replaces ~210k device-scope atomicAdd RMWs with pipelined plain stores.
__global__ __launch_bounds__(256) void simexp_mfma(const unsigned char* __restrict__ zn,
                                                   float* __restrict__ PART,
                                                   float* __restrict__ pos) {
    __shared__ __align__(16) unsigned char As[2][128 * 64];   // 2 x 8 KB
    __shared__ __align__(16) unsigned char Bs[2][128 * 64];   // 2 x 8 KB
    // decode upper-triangle tile index (scalar, uniform)
    int t = blockIdx.x, rt = 0, rem = NT_;
    while (t >= rem) { t -= rem; rem--; rt++; }
    int ct = rt + t;

    int tid = threadIdx.x;
    int wid = tid >> 6, lane = tid & 63;
    int lrow = lane >> 2, lk = lane & 3;        // staging: 16 rows x 4 chunks of 16B
    int lx = lane & 15, quad = lane >> 4;       // mfma fragment indexing
    int wrow = (wid >> 1) * 64, wcol = (wid & 1) * 64;

    const unsigned char* gA[2]; const unsigned char* gB[2];
    int loff[2];
#pragma unroll
    for (int c = 0; c < 2; ++c) {
        int r = wid * 32 + c * 16 + lrow;
        gA[c] = zn + (size_t)(rt * 128 + r) * CB4_ + ((lk ^ (lrow & 3)) * 16);
        gB[c] = zn + (size_t)(ct * 128 + r) * CB4_ + ((lk ^ (lrow & 3)) * 16);
        loff[c] = (wid * 32 + c * 16) * 64;     // HW appends lane*16B
    }

    union frag { int8v v8; int4v v4[2]; };
    floatx4 acc[4][4] = {};

    // prologue: stage iter 0 into buffer 0
#pragma unroll
    for (int c = 0; c < 2; ++c) {
        __builtin_amdgcn_global_load_lds(GAS(gA[c]), LAS(As[0] + loff[c]), 16, 0, 0);
        __builtin_amdgcn_global_load_lds(GAS(gB[c]), LAS(Bs[0] + loff[c]), 16, 0, 0);
    }

    for (int k = 0; k < 4; ++k) {               // 4 iters, 128 K-elems each
        int cur = k & 1, nxt = cur ^ 1;
        __syncthreads();                        // buf[cur] ready (vmcnt drained)
        if (k < 3) {                            // prefetch iter k+1 into buf[nxt]
            int k0 = (k + 1) * 64;
#pragma unroll
            for (int c = 0; c < 2; ++c) {
                __builtin_amdgcn_global_load_lds(GAS(gA[c] + k0), LAS(As[nxt] + loff[c]), 16, 0, 0);
                __builtin_amdgcn_global_load_lds(GAS(gB[c] + k0), LAS(Bs[nxt] + loff[c]), 16, 0, 0);
            }
        }
        frag af[4], bf[4];
#pragma unroll
        for (int tt = 0; tt < 4; ++tt) {
            int m = wrow + tt * 16 + lx;
            af[tt].v4[0] = *(const int4v*)&As[cur][m * 64 + ((quad ^ (m & 3)) * 16)];
            af[tt].v4[1] = (int4v)(0);
            int n = wcol + tt * 16 + lx;
            bf[tt].v4[0] = *(const int4v*)&Bs[cur][n * 64 + ((quad ^ (n & 3)) * 16)];
            bf[tt].v4[1] = (int4v)(0);
        }
#pragma unroll
        for (int i = 0; i < 4; ++i)
#pragma unroll
            for (int j = 0; j < 4; ++j)
                acc[i][j] = __builtin_amdgcn_mfma_scale_f32_16x16x128_f8f6f4(
                    af[i].v8, bf[j].v8, acc[i][j],
                    4, 4,                    // cbsz=fp4(e2m1), blgp=fp4(e2m1)
                    0, 0x7A7A7A7A,           // scale A: E8M0 2^-5
                    0, 0x7A7A7A7A);          // scale B: E8M0 2^-5
    }

    // epilogue: D layout col=lane&15, row=quad*4+reg (shape-determined)
    int colb = ct * 128 + wcol + lx;
    int rslot = ct * 2 + (wid & 1);             // row-partial slot (this col-half)
    int cslot = rt * 2 + (wid >> 1);            // col-partial slot (this row-half)
    if (rt == ct) {
        // diagonal tile: mask diagonal, row sums only (pos never here)
#pragma unroll
        for (int i = 0; i < 4; ++i) {
#pragma unroll
            for (int r = 0; r < 4; ++r) {
                int m = rt * 128 + wrow + i * 16 + quad * 4 + r;
                float s = 0.f;
#pragma unroll
                for (int j = 0; j < 4; ++j) {
                    int cg = colb + j * 16;
                    float e = __expf(acc[i][j][r] * TEMP_INV);
                    if (cg == m) e = 0.f;
                    s += e;
                }
                s += __shfl_xor(s, 1, 64);
                s += __shfl_xor(s, 2, 64);
                s += __shfl_xor(s, 4, 64);
                s += __shfl_xor(s, 8, 64);
                if (lx == 0) PART[m * NSLOT_ + rslot] = s;
            }
        }
    } else {
        // off-diagonal: row sums + column sums (transposed half), pos capture
        float colpart[4] = {0.f, 0.f, 0.f, 0.f};
#pragma unroll
        for (int i = 0; i < 4; ++i) {
#pragma unroll
            for (int r = 0; r < 4; ++r) {
                int m = rt * 128 + wrow + i * 16 + quad * 4 + r;
                int partner = m + BS_;          // only m<BS_ can hit in upper triangle
                float s = 0.f;
#pragma unroll
                for (int j = 0; j < 4; ++j) {
                    int cg = colb + j * 16;
                    float logit = acc[i][j][r] * TEMP_INV;
                    float e = __expf(logit);
                    if (cg == partner) { pos[m] = logit; pos[cg] = logit; }
                    s += e;
                    colpart[j] += e;
                }
                s += __shfl_xor(s, 1, 64);
                s += __shfl_xor(s, 2, 64);
                s += __shfl_xor(s, 4, 64);
                s += __shfl_xor(s, 8, 64);
                if (lx == 0) PART[m * NSLOT_ + rslot] = s;
            }
        }
#pragma unroll
        for (int j = 0; j < 4; ++j) {
            float cs = colpart[j];
            cs += __shfl_xor(cs, 16, 64);
            cs += __shfl_xor(cs, 32, 64);
            if (quad == 0) PART[(colb + j * 16) * NSLOT_ + cslot] = cs;
        }
    }
}

// ---- kernel 3: loss = sum(log(S) - pos) / N  (80 blocks, warp per row) -----
// Row m's denominator = sum of its 80 partial slots: slots [2q..79] are row
// partials from tiles (q, ct); slots [0..2q) are col partials from tiles
// (rt, q) — exactly 80 slots written per row, no zero-init needed.
__global__ __launch_bounds__(256) void loss_kernel(const float* __restrict__ PART,
                                                   const float* __restrict__ pos,
                                                   float* __restrict__ out) {
    int tid = threadIdx.x, lane = tid & 63, wid = tid >> 6;
    float acc = 0.f;
#pragma unroll
    for (int it = 0; it < 16; ++it) {
        int m = blockIdx.x * 64 + wid * 16 + it;
        float v = PART[m * NSLOT_ + lane];
        if (lane < 16) v += PART[m * NSLOT_ + 64 + lane];
#pragma unroll
        for (int s = 32; s >= 1; s >>= 1) v += __shfl_xor(v, s, 64);
        if (lane == 0) acc += logf(v) - pos[m];
    }
    __shared__ float part[4];
    if (lane == 0) part[wid] = acc;
    __syncthreads();
    if (tid == 0)
        atomicAdd(out, (part[0] + part[1] + part[2] + part[3]) * (1.0f / N_));
}

extern "C" void kernel_launch(void* const* d_in, const int* in_sizes, int n_in,
                              void* d_out, int out_size, void* d_ws, size_t ws_size,
                              hipStream_t stream) {
    const float* zi = (const float*)d_in[0];
    const float* zj = (const float*)d_in[1];
    float* out = (float*)d_out;

    char* ws = (char*)d_ws;
    unsigned char* zn = (unsigned char*)ws;                    // N_*256 B fp4 = 1.31 MB
    float* pos  = (float*)(ws + (size_t)N_ * CB4_);            // N_ floats
    float* PART = pos + N_;                                    // N_*80 floats = 1.64 MB

    pool_norm_kernel<<<N_ / 4, 256, 0, stream>>>(zi, zj, (uint*)zn, out);
    simexp_mfma<<<NTILES_, 256, 0, stream>>>(zn, PART, pos);
    loss_kernel<<<N_ / 64, 256, 0, stream>>>(PART, pos, out);
}

// Round 3
// 107.159 us; speedup vs baseline: 1.4200x; 1.0561x over previous
//
#include <hip/hip_runtime.h>
#include <hip/hip_bf16.h>
#include <math.h>

#define B_       512
#define SEQ_     25
#define C_       512
#define W_       5
#define BS_      2560          // B_*W_ rows per input
#define N_       5120          // 2*BS_
#define NT_      40            // N_/128 tile rows
#define NTILES_  (NT_ * (NT_ + 1) / 2)   // 820 upper-triangle tiles
#define CB4_     256           // bytes per zn row (512 fp4 nibbles)
#define TEMP_INV 10.0f
#define EPS_     1e-8f

typedef __attribute__((ext_vector_type(4))) int   int4v;
typedef __attribute__((ext_vector_type(8))) int   int8v;
typedef __attribute__((ext_vector_type(4))) float floatx4;

#define GAS(p) ((__attribute__((address_space(1))) void*)(void*)(p))
#define LAS(p) ((__attribute__((address_space(3))) void*)(p))

// e2m1 quantize of x (pre-scaled by 32): codes 0..7 = {0,.5,1,1.5,2,3,4,6}
static __device__ __forceinline__ uint fp4q(float x) {
    float m = fabsf(x);
    uint c;
    if      (m < 0.25f) c = 0;
    else if (m < 0.75f) c = 1;
    else if (m < 1.25f) c = 2;
    else if (m < 1.75f) c = 3;
    else if (m < 2.5f)  c = 4;
    else if (m < 3.5f)  c = 5;
    else if (m < 5.0f)  c = 6;
    else                c = 7;
    return c | (x < 0.f ? 8u : 0u);
}

// ---- kernel 1: pool (5-wide bins) + L2 normalize + fp4(e2m1) pack -----------
__global__ __launch_bounds__(256) void pool_norm_kernel(const float* __restrict__ zi,
                                                        const float* __restrict__ zj,
                                                        uint* __restrict__ zn4,
                                                        float* __restrict__ S,
                                                        float* __restrict__ out) {
    int row = blockIdx.x * 4 + (threadIdx.x >> 6);
    int lane = threadIdx.x & 63;
    const float* src = (row < BS_) ? zi : zj;
    int rr = (row < BS_) ? row : row - BS_;
    int b = rr / W_;
    int w = rr - b * W_;
    const float4* base4 = (const float4*)(src + ((size_t)b * SEQ_ + (size_t)w * W_) * C_);
    float4 v0 = {0, 0, 0, 0}, v1 = {0, 0, 0, 0};
#pragma unroll
    for (int t = 0; t < W_; ++t) {
        float4 a = base4[t * 128 + lane * 2];
        float4 c = base4[t * 128 + lane * 2 + 1];
        v0.x += a.x; v0.y += a.y; v0.z += a.z; v0.w += a.w;
        v1.x += c.x; v1.y += c.y; v1.z += c.z; v1.w += c.w;
    }
    float ss = v0.x * v0.x + v0.y * v0.y + v0.z * v0.z + v0.w * v0.w
             + v1.x * v1.x + v1.y * v1.y + v1.z * v1.z + v1.w * v1.w;
#pragma unroll
    for (int m = 32; m >= 1; m >>= 1) ss += __shfl_xor(ss, m, 64);
    // 1/5 pooling scale folds into 1/norm (cosine is scale-invariant)
    float inv32 = 32.0f / fmaxf(sqrtf(ss), EPS_);
    uint p = fp4q(v0.x * inv32);
    p |= fp4q(v0.y * inv32) << 4;
    p |= fp4q(v0.z * inv32) << 8;
    p |= fp4q(v0.w * inv32) << 12;
    p |= fp4q(v1.x * inv32) << 16;
    p |= fp4q(v1.y * inv32) << 20;
    p |= fp4q(v1.z * inv32) << 24;
    p |= fp4q(v1.w * inv32) << 28;
    zn4[(size_t)row * 64 + lane] = p;
    if (lane == 0) S[row] = 0.f;                    // replaces memset launch
    if (row == 0 && lane == 0) out[0] = 0.f;        // loss accumulator init
}

// ---- kernel 2: upper-tri 128x128 tiles, MX-fp4, double-buffered staging -----
// R4 structure (4 K-iters of 64B/row) + ping-pong LDS: iter k+1's
// global_load_lds issue right after the barrier, ahead of iter k's MFMAs, so
// L2 latency hides behind compute instead of serializing at each drain.
// NOTE (R1/R2 post-mortems): atomicAdd to S is NOT a bottleneck (atomic-free
// PART rewrite was neutral-to-worse); per-block __threadfence costs ~45 µs
// total (L2 writeback x820) — keep atomics, no fences, separate loss kernel.
__global__ __launch_bounds__(256) void simexp_mfma(const unsigned char* __restrict__ zn,
                                                   float* __restrict__ S,
                                                   float* __restrict__ pos) {
    __shared__ __align__(16) unsigned char As[2][128 * 64];   // 2 x 8 KB
    __shared__ __align__(16) unsigned char Bs[2][128 * 64];   // 2 x 8 KB
    // decode upper-triangle tile index (scalar, uniform)
    int t = blockIdx.x, rt = 0, rem = NT_;
    while (t >= rem) { t -= rem; rem--; rt++; }
    int ct = rt + t;

    int tid = threadIdx.x;
    int wid = tid >> 6, lane = tid & 63;
    int lrow = lane >> 2, lk = lane & 3;        // staging: 16 rows x 4 chunks of 16B
    int lx = lane & 15, quad = lane >> 4;       // mfma fragment indexing
    int wrow = (wid >> 1) * 64, wcol = (wid & 1) * 64;

    const unsigned char* gA[2]; const unsigned char* gB[2];
    int loff[2];
#pragma unroll
    for (int c = 0; c < 2; ++c) {
        int r = wid * 32 + c * 16 + lrow;
        gA[c] = zn + (size_t)(rt * 128 + r) * CB4_ + ((lk ^ (lrow & 3)) * 16);
        gB[c] = zn + (size_t)(ct * 128 + r) * CB4_ + ((lk ^ (lrow & 3)) * 16);
        loff[c] = (wid * 32 + c * 16) * 64;     // HW appends lane*16B
    }

    union frag { int8v v8; int4v v4[2]; };
    floatx4 acc[4][4] = {};

    // prologue: stage iter 0 into buffer 0
#pragma unroll
    for (int c = 0; c < 2; ++c) {
        __builtin_amdgcn_global_load_lds(GAS(gA[c]), LAS(As[0] + loff[c]), 16, 0, 0);
        __builtin_amdgcn_global_load_lds(GAS(gB[c]), LAS(Bs[0] + loff[c]), 16, 0, 0);
    }

    for (int k = 0; k < 4; ++k) {               // 4 iters, 128 K-elems each
        int cur = k & 1, nxt = cur ^ 1;
        __syncthreads();                        // buf[cur] ready (vmcnt drained)
        if (k < 3) {                            // prefetch iter k+1 into buf[nxt]
            int k0 = (k + 1) * 64;
#pragma unroll
            for (int c = 0; c < 2; ++c) {
                __builtin_amdgcn_global_load_lds(GAS(gA[c] + k0), LAS(As[nxt] + loff[c]), 16, 0, 0);
                __builtin_amdgcn_global_load_lds(GAS(gB[c] + k0), LAS(Bs[nxt] + loff[c]), 16, 0, 0);
            }
        }
        frag af[4], bf[4];
#pragma unroll
        for (int tt = 0; tt < 4; ++tt) {
            int m = wrow + tt * 16 + lx;
            af[tt].v4[0] = *(const int4v*)&As[cur][m * 64 + ((quad ^ (m & 3)) * 16)];
            af[tt].v4[1] = (int4v)(0);
            int n = wcol + tt * 16 + lx;
            bf[tt].v4[0] = *(const int4v*)&Bs[cur][n * 64 + ((quad ^ (n & 3)) * 16)];
            bf[tt].v4[1] = (int4v)(0);
        }
#pragma unroll
        for (int i = 0; i < 4; ++i)
#pragma unroll
            for (int j = 0; j < 4; ++j)
                acc[i][j] = __builtin_amdgcn_mfma_scale_f32_16x16x128_f8f6f4(
                    af[i].v8, bf[j].v8, acc[i][j],
                    4, 4,                    // cbsz=fp4(e2m1), blgp=fp4(e2m1)
                    0, 0x7A7A7A7A,           // scale A: E8M0 2^-5
                    0, 0x7A7A7A7A);          // scale B: E8M0 2^-5
    }

    // epilogue: D layout col=lane&15, row=quad*4+reg (shape-determined)
    int colb = ct * 128 + wcol + lx;
    if (rt == ct) {
        // diagonal tile: mask diagonal, row sums only (pos never here)
#pragma unroll
        for (int i = 0; i < 4; ++i) {
#pragma unroll
            for (int r = 0; r < 4; ++r) {
                int m = rt * 128 + wrow + i * 16 + quad * 4 + r;
                float s = 0.f;
#pragma unroll
                for (int j = 0; j < 4; ++j) {
                    int cg = colb + j * 16;
                    float e = __expf(acc[i][j][r] * TEMP_INV);
                    if (cg == m) e = 0.f;
                    s += e;
                }
                s += __shfl_xor(s, 1, 64);
                s += __shfl_xor(s, 2, 64);
                s += __shfl_xor(s, 4, 64);
                s += __shfl_xor(s, 8, 64);
                if (lx == 0) atomicAdd(&S[m], s);
            }
        }
    } else {
        // off-diagonal: row sums + column sums (transposed half), pos capture
        float colpart[4] = {0.f, 0.f, 0.f, 0.f};
#pragma unroll
        for (int i = 0; i < 4; ++i) {
#pragma unroll
            for (int r = 0; r < 4; ++r) {
                int m = rt * 128 + wrow + i * 16 + quad * 4 + r;
                int partner = m + BS_;          // only m<BS_ can hit in upper triangle
                float s = 0.f;
#pragma unroll
                for (int j = 0; j < 4; ++j) {
                    int cg = colb + j * 16;
                    float logit = acc[i][j][r] * TEMP_INV;
                    float e = __expf(logit);
                    if (cg == partner) { pos[m] = logit; pos[cg] = logit; }
                    s += e;
                }
                s += __shfl_xor(s, 1, 64);
                s += __shfl_xor(s, 2, 64);
                s += __shfl_xor(s, 4, 64);
                s += __shfl_xor(s, 8, 64);
                if (lx == 0) atomicAdd(&S[m], s);
            }
        }
        // colpart recompute avoided: accumulate during j-loop above would
        // double register pressure in the unrolled body; instead reduce the
        // transposed half directly from acc (same values, different order).
#pragma unroll
        for (int j = 0; j < 4; ++j) {
            float cs = 0.f;
#pragma unroll
            for (int i = 0; i < 4; ++i)
#pragma unroll
                for (int r = 0; r < 4; ++r)
                    cs += __expf(acc[i][j][r] * TEMP_INV);
            cs += __shfl_xor(cs, 16, 64);
            cs += __shfl_xor(cs, 32, 64);
            if (quad == 0) atomicAdd(&S[colb + j * 16], cs);
        }
    }
}

// ---- kernel 3: loss = sum(log(S) - pos) / N  (20 blocks, atomic accumulate) -
__global__ __launch_bounds__(256) void loss_kernel(const float* __restrict__ S,
                                                   const float* __restrict__ pos,
                                                   float* __restrict__ out) {
    int i = blockIdx.x * 256 + threadIdx.x;
    float a = logf(S[i]) - pos[i];
#pragma unroll
    for (int m = 32; m >= 1; m >>= 1) a += __shfl_xor(a, m, 64);
    __shared__ float part[4];
    int lane = threadIdx.x & 63, wid = threadIdx.x >> 6;
    if (lane == 0) part[wid] = a;
    __syncthreads();
    if (threadIdx.x == 0)
        atomicAdd(out, (part[0] + part[1] + part[2] + part[3]) * (1.0f / N_));
}

extern "C" void kernel_launch(void* const* d_in, const int* in_sizes, int n_in,
                              void* d_out, int out_size, void* d_ws, size_t ws_size,
                              hipStream_t stream) {
    const float* zi = (const float*)d_in[0];
    const float* zj = (const float*)d_in[1];
    float* out = (float*)d_out;

    char* ws = (char*)d_ws;
    unsigned char* zn = (unsigned char*)ws;                    // N_*256 B fp4 = 1.31 MB
    float* S   = (float*)(ws + (size_t)N_ * CB4_);
    float* pos = S + N_;

    pool_norm_kernel<<<N_ / 4, 256, 0, stream>>>(zi, zj, (uint*)zn, S, out);
    simexp_mfma<<<NTILES_, 256, 0, stream>>>(zn, S, pos);
    loss_kernel<<<N_ / 256, 256, 0, stream>>>(S, pos, out);
}